// Round 11
// baseline (1117.264 us; speedup 1.0000x reference)
//
#include <hip/hip_runtime.h>

#define NN 20000
#define NK 2
#define FC 256    // combined width
#define FH 128    // hidden width
#define NE 640000
#define NB 21     // weight blocks
#define ELLW 96   // ELL slots per row (multiple of 32); P(Binom(640k,1/20k) > 96) ~ 1e-20

typedef short v8s __attribute__((ext_vector_type(8)));
typedef float v4f __attribute__((ext_vector_type(4)));
typedef unsigned int uint;
typedef uint v4u __attribute__((ext_vector_type(4)));

__device__ __forceinline__ float bf2f(unsigned short h) {
    union { uint u; float f; } v; v.u = ((uint)h) << 16; return v.f;
}
__device__ __forceinline__ unsigned short f2bf(float f) {
    union { float f; uint u; } v; v.f = f;
    uint r = v.u + 0x7FFF + ((v.u >> 16) & 1);   // RNE
    return (unsigned short)(r >> 16);
}
__device__ __forceinline__ float bflo(uint v) {
    union { uint u; float f; } t; t.u = v << 16; return t.f;
}
__device__ __forceinline__ float bfhi(uint v) {
    union { uint u; float f; } t; t.u = v & 0xffff0000u; return t.f;
}

// ---------------- ELL build: one pass (meta uint = (w_bf16 << 16) | src) ----------------

__global__ __launch_bounds__(256) void k_fill(const int* __restrict__ ei, const float* __restrict__ ew,
                                              int* __restrict__ cnt, uint* __restrict__ ell) {
    int wg = blockIdx.x;                    // 20000 = 8 * 2500
    int xcd = wg & 7, chunk = wg >> 3;
    int k = xcd & 1, q = xcd >> 1;
    int e = chunk * 256 + threadIdx.x;
    int dst = __builtin_nontemporal_load(ei + (size_t)k * 2 * NE + NE + e);
    if (dst >= q * 5000 && dst < q * 5000 + 5000) {
        int src = __builtin_nontemporal_load(ei + (size_t)k * 2 * NE + e);
        float w = __builtin_nontemporal_load(ew + (size_t)k * NE + e);
        int slot = atomicAdd(&cnt[k * NN + dst], 1);
        if (slot < ELLW)
            ell[((size_t)k * NN + dst) * ELLW + slot] = (uint)src | ((uint)f2bf(w) << 16);
    }
}

// ---------------- combined build (bf16) ----------------

__global__ __launch_bounds__(256) void k_comb(const float* __restrict__ in, const float* __restrict__ hid,
                                              unsigned short* __restrict__ comb) {
    int i = blockIdx.x * 256 + threadIdx.x;          // 0 .. NN*64-1
    int r = i >> 6, c4 = i & 63;
    float4 v = (c4 < 32) ? ((const float4*)(in  + (size_t)r * FH))[c4]
                         : ((const float4*)(hid + (size_t)r * FH))[c4 - 32];
    ushort4 o; o.x = f2bf(v.x); o.y = f2bf(v.y); o.z = f2bf(v.z); o.w = f2bf(v.w);
    *(ushort4*)&comb[(size_t)r * FC + c4 * 4] = o;
}

// ---------------- W convert + transpose: Wt[blk][n][k] bf16 ----------------

__global__ __launch_bounds__(256) void k_wcvt(const float* __restrict__ W, unsigned short* __restrict__ Wt) {
    int i = blockIdx.x * 256 + threadIdx.x;          // NB*FH*FC = 688128
    int blk = i >> 15;
    int rem = i & 32767;
    int n = rem >> 8, kk = rem & 255;
    Wt[i] = f2bf(W[((size_t)blk * FC + kk) * FH + n]);
}

// ---------------- MFMA GEMM ----------------
// outf != 0 (gy=1): identity block (blk 0) -> fp32 outf, row-major.
// else (gy=4): by -> support (by&1), dj (by>>1); blk = (jstep-dj) + 10*(by&1);
//              write bf16 SPLIT layout [k][h][NN][64] into (dj ? obB : obA).

#define LDK 72

__global__ __launch_bounds__(256, 2) void k_gemm(const unsigned short* __restrict__ X,
        const unsigned short* __restrict__ Wt, unsigned short* __restrict__ obA,
        unsigned short* __restrict__ obB, float* __restrict__ outf, int jstep) {
    __shared__ unsigned short Xs[64 * LDK];
    __shared__ unsigned short Ws[128 * LDK];
    int t = threadIdx.x;
    int w = t >> 6, l = t & 63;
    int l15 = l & 15, lg = l >> 4;
    int bm = blockIdx.x * 64;
    int by = blockIdx.y;
    int sup = by & 1, dj = by >> 1;
    int blk = outf ? 0 : ((jstep - dj) + 10 * sup);
    const unsigned short* Wb = Wt + (size_t)blk * FH * FC;
    v4f acc[4][2];
#pragma unroll
    for (int a = 0; a < 4; ++a)
#pragma unroll
        for (int b = 0; b < 2; ++b) acc[a][b] = (v4f){0.f, 0.f, 0.f, 0.f};

    for (int c = 0; c < 4; ++c) {
#pragma unroll
        for (int i = 0; i < 2; ++i) {                 // X tile: 64x64 bf16
            int s = t + i * 256;
            int row = s >> 3, c8 = s & 7;
            int grow = bm + row; if (grow >= NN) grow = NN - 1;
            *(v8s*)&Xs[row * LDK + c8 * 8] = *(const v8s*)(X + (size_t)grow * FC + c * 64 + c8 * 8);
        }
#pragma unroll
        for (int i = 0; i < 4; ++i) {                 // W tile: 128 n x 64 k
            int s = t + i * 256;
            int n = s >> 3, k8 = s & 7;
            *(v8s*)&Ws[n * LDK + k8 * 8] = *(const v8s*)(Wb + (size_t)n * FC + c * 64 + k8 * 8);
        }
        __syncthreads();
#pragma unroll
        for (int ks2 = 0; ks2 < 2; ++ks2) {
            int ko = ks2 * 32 + lg * 8;
            v8s a[4], b[2];
#pragma unroll
            for (int mf = 0; mf < 4; ++mf) a[mf] = *(const v8s*)&Xs[(mf * 16 + l15) * LDK + ko];
#pragma unroll
            for (int nf = 0; nf < 2; ++nf) b[nf] = *(const v8s*)&Ws[(w * 32 + nf * 16 + l15) * LDK + ko];
#pragma unroll
            for (int mf = 0; mf < 4; ++mf)
#pragma unroll
                for (int nf = 0; nf < 2; ++nf)
                    acc[mf][nf] = __builtin_amdgcn_mfma_f32_16x16x32_bf16(a[mf], b[nf], acc[mf][nf], 0, 0, 0);
        }
        __syncthreads();
    }
    unsigned short* ob = (dj ? obB : obA);
    if (ob) ob += (size_t)sup * NN * FH;
#pragma unroll
    for (int mf = 0; mf < 4; ++mf) {
        int grow0 = bm + mf * 16 + lg * 4;           // C/D: col=lane&15, row=(lane>>4)*4+reg  [m89]
#pragma unroll
        for (int nf = 0; nf < 2; ++nf) {
            int gcol = w * 32 + nf * 16 + l15;
            int hh = gcol >> 6, c63 = gcol & 63;
#pragma unroll
            for (int r = 0; r < 4; ++r) {
                int grow = grow0 + r;
                if (grow < NN) {
                    if (outf) outf[(size_t)grow * FH + gcol] = acc[mf][nf][r];
                    else      ob[((size_t)hh * NN + grow) * 64 + c63] = f2bf(acc[mf][nf][r]);
                }
            }
        }
    }
}

// ---------------- Clenshaw SPMM: 8 slots x 8 lanes, v4u gathers, zero-padded ELL ----------------
// 8 XCD groups (k,h,row-half): 2.56MB gather set per XCD (L2-resident, r8/r9-proven).
// One gather instr = 8 edges x 128B half-row; one meta broadcast-load = 8 edges.
// Avg degree 32 => single loop iteration, 4 independent meta->gather chains, no guards
// (ELL zero-padded: w=0, src=0). Meta loads nt so the stream doesn't evict the gather set.
// mode 0: out = y + 2*(A b1) ; mode 1: ... - b2 ; mode 2: out = (A b1) - b2

__global__ __launch_bounds__(256) void k_spmm(const int* __restrict__ cnt, const uint* __restrict__ ell,
        const v4u* __restrict__ b1, const v4u* __restrict__ b2,
        const v4u* __restrict__ y, v4u* __restrict__ outp, int mode) {
    int wg = blockIdx.x;                 // 20000 = 8 groups x 2500
    int g = wg & 7, slot = wg >> 3;
    int k = g >> 2, h = (g >> 1) & 1, rh = g & 1;
    int lane = threadIdx.x & 63;
    int l7 = lane & 7, sl = lane >> 3;             // 8 edge-slots of 8 lanes
    int row = (rh * 2500 + slot) * 4 + (threadIdx.x >> 6);
    int d = cnt[k * NN + row];
    if (d > ELLW) d = ELLW;
    const uint* __restrict__ er = ell + ((size_t)k * NN + row) * ELLW;
    const v4u* __restrict__ gb = b1 + (size_t)(k * 2 + h) * NN * 8;   // row = 8 v4u (128B)

    size_t o = ((size_t)(k * 2 + h) * NN + row) * 8 + l7;
    v4u yv = (v4u){0, 0, 0, 0}, bv = (v4u){0, 0, 0, 0};
    if (mode != 2) yv = __builtin_nontemporal_load(y + o);    // hoisted under edge loop
    if (mode != 0) bv = b2[o];

    float a0 = 0.f, a1 = 0.f, a2 = 0.f, a3 = 0.f, a4 = 0.f, a5 = 0.f, a6 = 0.f, a7 = 0.f;

    for (int e0 = 0; e0 < d; e0 += 32) {
#pragma unroll
        for (int u = 0; u < 4; ++u) {              // 4 independent chains x 8 edges
            uint m = __builtin_nontemporal_load(er + e0 + u * 8 + sl);  // 8-lane broadcast
            float w = bfhi(m);                     // weight bf16 in high 16; 0 on pad
            v4u vv = gb[(uint)((m & 0xffffu) * 8 + l7)];
            a0 += w * bflo(vv.x); a1 += w * bfhi(vv.x);
            a2 += w * bflo(vv.y); a3 += w * bfhi(vv.y);
            a4 += w * bflo(vv.z); a5 += w * bfhi(vv.z);
            a6 += w * bflo(vv.w); a7 += w * bfhi(vv.w);
        }
    }

    // reduce across the 8 slots (lane bits 3,4,5)
    a0 += __shfl_xor(a0, 8);  a1 += __shfl_xor(a1, 8);  a2 += __shfl_xor(a2, 8);  a3 += __shfl_xor(a3, 8);
    a4 += __shfl_xor(a4, 8);  a5 += __shfl_xor(a5, 8);  a6 += __shfl_xor(a6, 8);  a7 += __shfl_xor(a7, 8);
    a0 += __shfl_xor(a0, 16); a1 += __shfl_xor(a1, 16); a2 += __shfl_xor(a2, 16); a3 += __shfl_xor(a3, 16);
    a4 += __shfl_xor(a4, 16); a5 += __shfl_xor(a5, 16); a6 += __shfl_xor(a6, 16); a7 += __shfl_xor(a7, 16);
    a0 += __shfl_xor(a0, 32); a1 += __shfl_xor(a1, 32); a2 += __shfl_xor(a2, 32); a3 += __shfl_xor(a3, 32);
    a4 += __shfl_xor(a4, 32); a5 += __shfl_xor(a5, 32); a6 += __shfl_xor(a6, 32); a7 += __shfl_xor(a7, 32);

    if (lane < 8) {
        float r0, r1, r2, r3, r4, r5, r6, r7;
        if (mode == 0) {
            r0 = bflo(yv.x) + 2.f * a0; r1 = bfhi(yv.x) + 2.f * a1;
            r2 = bflo(yv.y) + 2.f * a2; r3 = bfhi(yv.y) + 2.f * a3;
            r4 = bflo(yv.z) + 2.f * a4; r5 = bfhi(yv.z) + 2.f * a5;
            r6 = bflo(yv.w) + 2.f * a6; r7 = bfhi(yv.w) + 2.f * a7;
        } else if (mode == 1) {
            r0 = bflo(yv.x) + 2.f * a0 - bflo(bv.x); r1 = bfhi(yv.x) + 2.f * a1 - bfhi(bv.x);
            r2 = bflo(yv.y) + 2.f * a2 - bflo(bv.y); r3 = bfhi(yv.y) + 2.f * a3 - bfhi(bv.y);
            r4 = bflo(yv.z) + 2.f * a4 - bflo(bv.z); r5 = bfhi(yv.z) + 2.f * a5 - bfhi(bv.z);
            r6 = bflo(yv.w) + 2.f * a6 - bflo(bv.w); r7 = bfhi(yv.w) + 2.f * a7 - bfhi(bv.w);
        } else {
            r0 = a0 - bflo(bv.x); r1 = a1 - bfhi(bv.x);
            r2 = a2 - bflo(bv.y); r3 = a3 - bfhi(bv.y);
            r4 = a4 - bflo(bv.z); r5 = a5 - bfhi(bv.z);
            r6 = a6 - bflo(bv.w); r7 = a7 - bfhi(bv.w);
        }
        v4u res;
        res.x = (uint)f2bf(r0) | ((uint)f2bf(r1) << 16);
        res.y = (uint)f2bf(r2) | ((uint)f2bf(r3) << 16);
        res.z = (uint)f2bf(r4) | ((uint)f2bf(r5) << 16);
        res.w = (uint)f2bf(r6) | ((uint)f2bf(r7) << 16);
        outp[o] = res;                             // regular store: next step's gather operand
    }
}

// ---------------- activations (Sk in split layout [k][h][NN][64]) ----------------

__global__ __launch_bounds__(256) void k_act(const float* __restrict__ S0, const unsigned short* __restrict__ Sk,
        const float* __restrict__ bvec, const float* __restrict__ hid,
        float* __restrict__ rbuf, unsigned short* __restrict__ comb) {
    int i = blockIdx.x * 256 + threadIdx.x;          // NN*128
    int r = i >> 7, c = i & 127;
    int h = c >> 6, c63 = c & 63;
    float s = S0[i] + bf2f(Sk[((size_t)h * NN + r) * 64 + c63])
                    + bf2f(Sk[((size_t)(2 + h) * NN + r) * 64 + c63]) + bvec[c];
    float u = 1.f / (1.f + __expf(-s));
    rbuf[i] = u;
    comb[(size_t)r * FC + FH + c] = f2bf(u * hid[i]);
}

__global__ __launch_bounds__(256) void k_final(const float* __restrict__ S0, const unsigned short* __restrict__ Sk,
        const float* __restrict__ bvec, const float* __restrict__ hid,
        const float* __restrict__ rbuf, float* __restrict__ out) {
    int i = blockIdx.x * 256 + threadIdx.x;
    int r = i >> 7, c = i & 127;
    int h = c >> 6, c63 = c & 63;
    float s = S0[i] + bf2f(Sk[((size_t)h * NN + r) * 64 + c63])
                    + bf2f(Sk[((size_t)(2 + h) * NN + r) * 64 + c63]) + bvec[c];
    float C = 1.f / (1.f + __expf(-s));
    float u = rbuf[i];
    out[i] = u * hid[i] + (1.f - u) * C;
}

// ---------------- launch ----------------

extern "C" void kernel_launch(void* const* d_in, const int* in_sizes, int n_in,
                              void* d_out, int out_size, void* d_ws, size_t ws_size,
                              hipStream_t stream) {
    const float* inp = (const float*)d_in[0];
    const float* hid = (const float*)d_in[1];
    const int*   ei  = (const int*)d_in[2];
    const float* ew  = (const float*)d_in[3];
    const float* W   = (const float*)d_in[4];
    const float* bv  = (const float*)d_in[5];
    float* out = (float*)d_out;

    char* base = (char*)d_ws;
    size_t off = 0;
    auto carve = [&](size_t bytes) -> char* {
        char* q = base + off;
        off += (bytes + 255) & ~(size_t)255;
        return q;
    };
    int*            cnt  = (int*)carve((size_t)2 * NN * 4);
    uint*           ell  = (uint*)carve((size_t)2 * NN * ELLW * 4);
    unsigned short* comb = (unsigned short*)carve((size_t)NN * FC * 2);
    unsigned short* Wt   = (unsigned short*)carve((size_t)NB * FH * FC * 2);
    unsigned short* ytA  = (unsigned short*)carve((size_t)2 * NN * FH * 2);
    unsigned short* ytB  = (unsigned short*)carve((size_t)2 * NN * FH * 2);
    unsigned short* Bs0  = (unsigned short*)carve((size_t)2 * NN * FH * 2);
    unsigned short* Bs1  = (unsigned short*)carve((size_t)2 * NN * FH * 2);
    unsigned short* Bs2  = (unsigned short*)carve((size_t)2 * NN * FH * 2);
    float*          Sacc = (float*)carve((size_t)NN * FH * 4);
    float*          rbuf = (float*)carve((size_t)NN * FH * 4);
    unsigned short* Bsl[3] = {Bs0, Bs1, Bs2};

    hipMemsetAsync(cnt, 0, (size_t)2 * NN * 4, stream);
    hipMemsetAsync(ell, 0, (size_t)2 * NN * ELLW * 4, stream);   // zero-pad: w=0, src=0
    k_fill<<<20000, 256, 0, stream>>>(ei, ew, cnt, ell);
    k_comb<<<5000, 256, 0, stream>>>(inp, hid, comb);
    k_wcvt<<<2688, 256, 0, stream>>>(W, Wt);

    auto gemmId = [&]() {   // identity block -> fp32 Sacc
        k_gemm<<<dim3(313, 1), 256, 0, stream>>>(comb, Wt, nullptr, nullptr, Sacc, 0);
    };
    auto gemmPair = [&](int j, unsigned short* oA, unsigned short* oB) {  // y_j -> oA, y_{j-1} -> oB
        k_gemm<<<dim3(313, 4), 256, 0, stream>>>(comb, Wt, oA, oB, nullptr, j);
    };
    auto spmm = [&](unsigned short* b1, unsigned short* b2, unsigned short* y,
                    unsigned short* o, int mode) {
        k_spmm<<<20000, 256, 0, stream>>>(cnt, ell, (const v4u*)b1, (const v4u*)b2,
                                          (const v4u*)y, (v4u*)o, mode);
    };

    // one gconv: returns the bf16 buffer holding per-support S_k = A b1 - b2 (both supports)
    auto gconv = [&]() -> unsigned short* {
        gemmId();
        gemmPair(10, Bsl[0], ytA);                   // b10 = y10 -> Bs0 ; y9 -> ytA
        spmm(Bsl[0], nullptr, ytA, Bsl[1], 0);       // b9 = y9 + 2A b10
        int cur = 1, prev = 0;
        for (int jp = 8; jp >= 2; jp -= 2) {
            gemmPair(jp, ytA, ytB);                  // y_jp -> ytA, y_{jp-1} -> ytB
            int nxt = 3 - cur - prev;
            spmm(Bsl[cur], Bsl[prev], ytA, Bsl[nxt], 1);
            prev = cur; cur = nxt;
            nxt = 3 - cur - prev;
            spmm(Bsl[cur], Bsl[prev], ytB, Bsl[nxt], 1);
            prev = cur; cur = nxt;
        }
        int fr = 3 - cur - prev;
        spmm(Bsl[cur], Bsl[prev], nullptr, Bsl[fr], 2);  // S_k = A b1 - b2
        return Bsl[fr];
    };

    // gconv #1 on [input, hidden] -> u (== r; reference computes it twice identically)
    unsigned short* S1 = gconv();
    k_act<<<10000, 256, 0, stream>>>(Sacc, S1, bv, hid, rbuf, comb);  // comb := [input, r*hidden]
    // gconv #2 on [input, r*hidden] -> C pre-activation
    unsigned short* S2 = gconv();
    k_final<<<10000, 256, 0, stream>>>(Sacc, S2, bv, hid, rbuf, out);
}